// Round 1
// baseline (509.830 us; speedup 1.0000x reference)
//
#include <hip/hip_runtime.h>
#include <hip/hip_bf16.h>
#include <stdint.h>

// ---------------- types & helpers ----------------
typedef __attribute__((ext_vector_type(8))) __bf16 bf16x8;
typedef __attribute__((ext_vector_type(4))) float f32x4;

#define CDIM 2048
#define DDIM 512

__device__ __forceinline__ unsigned short f2bf(float f) {
  union { float f; unsigned u; } a; a.f = f;
  unsigned r = a.u + 0x7FFFu + ((a.u >> 16) & 1u);   // RNE to bf16
  return (unsigned short)(r >> 16);
}
__device__ __forceinline__ float bf2f(unsigned short h) {
  union { unsigned u; float f; } a; a.u = ((unsigned)h) << 16;
  return a.f;
}

typedef const __attribute__((address_space(1))) void gas_void;
typedef __attribute__((address_space(3))) void las_void;
__device__ __forceinline__ void async16(const void* g, void* l) {
  // wave-uniform LDS base; HW adds lane*16 (guide §5)
  __builtin_amdgcn_global_load_lds((gas_void*)g, (las_void*)l, 16, 0, 0);
}

__device__ __forceinline__ float blockSum256(float v) {
  __shared__ float sh[4];
  #pragma unroll
  for (int o = 32; o; o >>= 1) v += __shfl_xor(v, o, 64);
  int lane = threadIdx.x & 63, w = threadIdx.x >> 6;
  __syncthreads();
  if (lane == 0) sh[w] = v;
  __syncthreads();
  return sh[0] + sh[1] + sh[2] + sh[3];
}

// ---------------- K0: fp32 -> bf16 conversion ----------------
__global__ __launch_bounds__(256) void k_convert(const float* __restrict__ x,
    const float* __restrict__ w, uint2* __restrict__ x16, uint2* __restrict__ w16) {
  const int nx4 = 15*1024*CDIM/4;
  const int nw4 = 15*DDIM*CDIM/4;
  int stride = gridDim.x * blockDim.x;
  for (int i = blockIdx.x*blockDim.x + threadIdx.x; i < nx4; i += stride) {
    float4 v = ((const float4*)x)[i];
    x16[i] = make_uint2((unsigned)f2bf(v.x) | ((unsigned)f2bf(v.y) << 16),
                        (unsigned)f2bf(v.z) | ((unsigned)f2bf(v.w) << 16));
  }
  for (int i = blockIdx.x*blockDim.x + threadIdx.x; i < nw4; i += stride) {
    float4 v = ((const float4*)w)[i];
    w16[i] = make_uint2((unsigned)f2bf(v.x) | ((unsigned)f2bf(v.y) << 16),
                        (unsigned)f2bf(v.z) | ((unsigned)f2bf(v.w) << 16));
  }
}

// ---------------- K1: total_k = [src_k; tgt] @ W_add[ik]^T + b_add (bf16 out) ----------------
// m97-structure: 128x128 tile, BK=64, 4 waves (2x2), 16x16x32 bf16 MFMA, global_load_lds x16.
__global__ __launch_bounds__(256) void k_gemm1(
    const unsigned short* __restrict__ x16,     // [15][1024][2048]
    const unsigned short* __restrict__ w16,     // [15][512][2048]
    const float* __restrict__ b_add,            // [15][512]
    const int* __restrict__ subj_p,
    unsigned short* __restrict__ t16)           // [14][2048][512]
{
  const int subj = *subj_p;
  int bid = blockIdx.x;
  int k  = bid >> 6;          // 64 tiles per k (16 m-tiles x 4 n-tiles)
  int t  = bid & 63;
  int mt = t >> 2, nt = t & 3;
  int ik = (k < subj) ? k : (k + 1);

  __shared__ unsigned short As[128*64];
  __shared__ unsigned short Bs[128*64];

  int tid = threadIdx.x;
  int lane = tid & 63;
  int w = tid >> 6;
  int wm = w >> 1, wn = w & 1;
  int rlane = lane >> 3;
  int col8  = (lane & 7) << 3;

  const unsigned short* Bbase = w16 + (size_t)ik * DDIM * CDIM;

  f32x4 acc[4][4];
  #pragma unroll
  for (int a = 0; a < 4; a++)
    #pragma unroll
    for (int b = 0; b < 4; b++) acc[a][b] = f32x4{0.f,0.f,0.f,0.f};

  for (int ks = 0; ks < CDIM; ks += 64) {
    #pragma unroll
    for (int i = 0; i < 4; i++) {
      int c = w*4 + i;               // chunk 0..15, 8 rows each
      int r = c*8 + rlane;           // tile row 0..127
      int gr = mt*128 + r;           // global row 0..2047
      int xrow = ((gr < 1024) ? ik : subj) * 1024 + (gr & 1023);
      async16(x16 + (size_t)xrow*CDIM + ks + col8, (char*)As + c*1024);
      int gn = nt*128 + r;           // W row (output col) 0..511
      async16(Bbase + (size_t)gn*CDIM + ks + col8, (char*)Bs + c*1024);
    }
    __syncthreads();
    #pragma unroll
    for (int kk = 0; kk < 64; kk += 32) {
      bf16x8 af[4], bfr[4];
      #pragma unroll
      for (int a = 0; a < 4; a++)
        af[a] = *(const bf16x8*)(As + (wm*64 + a*16 + (lane & 15))*64 + kk + ((lane >> 4) << 3));
      #pragma unroll
      for (int b = 0; b < 4; b++)
        bfr[b] = *(const bf16x8*)(Bs + (wn*64 + b*16 + (lane & 15))*64 + kk + ((lane >> 4) << 3));
      #pragma unroll
      for (int a = 0; a < 4; a++)
        #pragma unroll
        for (int b = 0; b < 4; b++)
          acc[a][b] = __builtin_amdgcn_mfma_f32_16x16x32_bf16(af[a], bfr[b], acc[a][b], 0, 0, 0);
    }
    __syncthreads();
  }
  const float* bias = b_add + ik*DDIM;
  #pragma unroll
  for (int b = 0; b < 4; b++) {
    int coln = nt*128 + wn*64 + b*16 + (lane & 15);
    float bv = bias[coln];
    #pragma unroll
    for (int a = 0; a < 4; a++) {
      #pragma unroll
      for (int r = 0; r < 4; r++) {
        int rowm = mt*128 + wm*64 + a*16 + ((lane >> 4) << 2) + r;   // C layout m89/m91
        t16[((size_t)k*2048 + rowm)*DDIM + coln] = f2bf(acc[a][b][r] + bv);
      }
    }
  }
}

// ---------------- K2a: per-row sq / softmax max / inv-sumexp ----------------
__global__ __launch_bounds__(256) void k_rowred(const unsigned short* __restrict__ t16,
    float* __restrict__ sq, float* __restrict__ rmax, float* __restrict__ rinv)
{
  int wid = blockIdx.x*4 + (threadIdx.x >> 6);   // 0..28671 = k*2048 + r
  int lane = threadIdx.x & 63;
  uint4 v = *(const uint4*)(t16 + (size_t)wid * DDIM + lane*8);
  unsigned uu[4] = {v.x, v.y, v.z, v.w};
  float f[8];
  #pragma unroll
  for (int q = 0; q < 4; q++) {
    f[2*q]   = bf2f((unsigned short)(uu[q] & 0xffffu));
    f[2*q+1] = bf2f((unsigned short)(uu[q] >> 16));
  }
  float s2 = 0.f, mx = -3.4e38f;
  #pragma unroll
  for (int j = 0; j < 8; j++) { s2 += f[j]*f[j]; mx = fmaxf(mx, f[j]); }
  #pragma unroll
  for (int o = 32; o; o >>= 1) { s2 += __shfl_xor(s2, o, 64); mx = fmaxf(mx, __shfl_xor(mx, o, 64)); }
  float se = 0.f;
  #pragma unroll
  for (int j = 0; j < 8; j++) se += __expf(f[j] - mx);
  #pragma unroll
  for (int o = 32; o; o >>= 1) se += __shfl_xor(se, o, 64);
  if (lane == 0) { sq[wid] = s2; rmax[wid] = mx; rinv[wid] = 1.f/se; }
}

// ---------------- K2b: column sums (for analytic sum(d2)) ----------------
__global__ __launch_bounds__(256) void k_colsum(const unsigned short* __restrict__ t16,
    float* __restrict__ scol)
{
  int b = blockIdx.x;              // 14*16
  int k = b >> 4, sub = b & 15;
  int d = ((sub & 1) << 8) + threadIdx.x;
  int r0 = (sub >> 1) << 8;
  const unsigned short* base = t16 + (size_t)k*2048*DDIM;
  float s = 0.f;
  for (int r = r0; r < r0 + 256; r++) s += bf2f(base[(size_t)r*DDIM + d]);
  atomicAdd(&scol[k*DDIM + d], s);
}

// ---------------- K2c: bandwidth -> exp2 coefficients ----------------
__global__ __launch_bounds__(256) void k_bw(const float* __restrict__ sq,
    const float* __restrict__ scol, float* __restrict__ c2)
{
  int k = blockIdx.x;
  float a = 0.f;
  for (int r = threadIdx.x; r < 2048; r += 256) a += sq[k*2048 + r];
  float b = 0.f;
  for (int d = threadIdx.x; d < 512; d += 256) { float v = scol[k*512 + d]; b += v*v; }
  float atot = blockSum256(a);
  float btot = blockSum256(b);
  if (threadIdx.x == 0) {
    // sum(d2) = 2m*sum(sq) - 2*|sum_rows|^2 ; bandwidth = sum/(m^2-m) / 2^(5//2)
    float sumd2 = 2.f*2048.f*atot - 2.f*btot;
    float bw = sumd2 / (2048.f*2048.f - 2048.f) * 0.25f;
    #pragma unroll
    for (int i = 0; i < 5; i++)
      c2[k*5 + i] = -1.4426950408889634f / (bw * (float)(1 << i));
  }
}

// ---------------- K2d: Gram + signed kernel-sum (MMD), upper-tri tiles ----------------
__global__ __launch_bounds__(256) void k_mmd(
    const unsigned short* __restrict__ t16,
    const float* __restrict__ sq,
    const float* __restrict__ c2,
    float* __restrict__ mmdacc)
{
  int bid = blockIdx.x;            // k*136 + tri
  int k = bid / 136;
  int tri = bid - k*136;
  int it = 0;
  while (tri >= 16 - it) { tri -= 16 - it; it++; }
  int jt = it + tri;               // it <= jt

  const unsigned short* T = t16 + (size_t)k * 2048 * DDIM;

  __shared__ unsigned short As[128*64];
  __shared__ unsigned short Bs[128*64];
  __shared__ float sqs[256];

  int tid = threadIdx.x;
  int lane = tid & 63;
  int w = tid >> 6;
  int wm = w >> 1, wn = w & 1;
  int rlane = lane >> 3;
  int col8  = (lane & 7) << 3;

  f32x4 acc[4][4];
  #pragma unroll
  for (int a = 0; a < 4; a++)
    #pragma unroll
    for (int b = 0; b < 4; b++) acc[a][b] = f32x4{0.f,0.f,0.f,0.f};

  for (int ks = 0; ks < DDIM; ks += 64) {
    #pragma unroll
    for (int i = 0; i < 4; i++) {
      int c = w*4 + i;
      int r = c*8 + rlane;
      async16(T + (size_t)(it*128 + r)*DDIM + ks + col8, (char*)As + c*1024);
      async16(T + (size_t)(jt*128 + r)*DDIM + ks + col8, (char*)Bs + c*1024);
    }
    __syncthreads();
    #pragma unroll
    for (int kk = 0; kk < 64; kk += 32) {
      bf16x8 af[4], bfr[4];
      #pragma unroll
      for (int a = 0; a < 4; a++)
        af[a] = *(const bf16x8*)(As + (wm*64 + a*16 + (lane & 15))*64 + kk + ((lane >> 4) << 3));
      #pragma unroll
      for (int b = 0; b < 4; b++)
        bfr[b] = *(const bf16x8*)(Bs + (wn*64 + b*16 + (lane & 15))*64 + kk + ((lane >> 4) << 3));
      #pragma unroll
      for (int a = 0; a < 4; a++)
        #pragma unroll
        for (int b = 0; b < 4; b++)
          acc[a][b] = __builtin_amdgcn_mfma_f32_16x16x32_bf16(af[a], bfr[b], acc[a][b], 0, 0, 0);
    }
    __syncthreads();
  }
  if (tid < 128) sqs[tid] = sq[k*2048 + it*128 + tid];
  else           sqs[tid] = sq[k*2048 + jt*128 + (tid - 128)];
  __syncthreads();

  float c0 = c2[k*5], c1 = c2[k*5+1], cA = c2[k*5+2], c3 = c2[k*5+3], c4 = c2[k*5+4];
  float part = 0.f;
  #pragma unroll
  for (int a = 0; a < 4; a++) {
    #pragma unroll
    for (int b = 0; b < 4; b++) {
      int rj = wn*64 + b*16 + (lane & 15);
      float sj = sqs[128 + rj];
      #pragma unroll
      for (int r = 0; r < 4; r++) {
        int ri = wm*64 + a*16 + ((lane >> 4) << 2) + r;
        float d2 = sqs[ri] + sj - 2.f*acc[a][b][r];
        part += exp2f(c0*d2) + exp2f(c1*d2) + exp2f(cA*d2) + exp2f(c3*d2) + exp2f(c4*d2);
      }
    }
  }
  float tot = blockSum256(part);
  if (tid == 0) {
    float sgn = ((it < 8) == (jt < 8)) ? 1.f : -1.f;   // XX/YY: + ; XY/YX: -
    float wgt = (it == jt) ? 1.f : 2.f;                 // symmetry
    atomicAdd(&mmdacc[k], sgn * wgt * tot);
  }
}

// ---------------- K3: disc pairwise |P_i - P_j| ----------------
__global__ __launch_bounds__(256) void k_disc(const unsigned short* __restrict__ t16,
    const float* __restrict__ rmax, const float* __restrict__ rinv, float* __restrict__ discacc)
{
  int b = blockIdx.x;              // 1024 rows x 2 half-rows
  int row = b >> 1;                // source rows only
  int d = ((b & 1) << 8) + threadIdx.x;
  float p[14];
  #pragma unroll
  for (int k = 0; k < 14; k++) {
    float tv = bf2f(t16[((size_t)(k*2048 + row))*DDIM + d]);
    p[k] = __expf(tv - rmax[k*2048 + row]) * rinv[k*2048 + row];
  }
  float s = 0.f;
  #pragma unroll
  for (int i2 = 0; i2 < 14; i2++)
    #pragma unroll
    for (int j2 = i2+1; j2 < 14; j2++)
      s += fabsf(p[i2] - p[j2]);
  float tot = blockSum256(s);
  if (threadIdx.x == 0) atomicAdd(discacc, tot);
}

// ---------------- K4: logits = relu(total) @ W_cls[k]^T + b_cls[k] ----------------
__global__ __launch_bounds__(256) void k_logits(const unsigned short* __restrict__ t16,
    const float* __restrict__ W_cls, const float* __restrict__ b_cls,
    float* __restrict__ logits)
{
  int wid = blockIdx.x*4 + (threadIdx.x >> 6);   // k*2048 + r
  int lane = threadIdx.x & 63;
  int k = wid >> 11;
  uint4 v = *(const uint4*)(t16 + (size_t)wid * DDIM + lane*8);
  unsigned uu[4] = {v.x, v.y, v.z, v.w};
  float f[8];
  #pragma unroll
  for (int q = 0; q < 4; q++) {
    f[2*q]   = fmaxf(bf2f((unsigned short)(uu[q] & 0xffffu)), 0.f);
    f[2*q+1] = fmaxf(bf2f((unsigned short)(uu[q] >> 16)), 0.f);
  }
  const float* Wc = W_cls + k*3*DDIM;
  int d0 = lane*8;
  float l0 = 0.f, l1 = 0.f, l2 = 0.f;
  #pragma unroll
  for (int j = 0; j < 8; j++) {
    l0 += f[j]*Wc[d0+j];
    l1 += f[j]*Wc[DDIM + d0+j];
    l2 += f[j]*Wc[2*DDIM + d0+j];
  }
  #pragma unroll
  for (int o = 32; o; o >>= 1) {
    l0 += __shfl_xor(l0, o, 64); l1 += __shfl_xor(l1, o, 64); l2 += __shfl_xor(l2, o, 64);
  }
  if (lane == 0) {
    logits[(size_t)wid*3 + 0] = l0 + b_cls[k*3 + 0];
    logits[(size_t)wid*3 + 1] = l1 + b_cls[k*3 + 1];
    logits[(size_t)wid*3 + 2] = l2 + b_cls[k*3 + 2];
  }
}

// ---------------- K5: cls KL (one-hot -> -logp[label]) ----------------
__global__ __launch_bounds__(256) void k_cls(const float* __restrict__ logits,
    const float* __restrict__ y, const int* __restrict__ subj_p, float* __restrict__ clsacc)
{
  int i = blockIdx.x*256 + threadIdx.x;    // 0..14335
  int k = i >> 10, r = i & 1023;
  int subj = *subj_p;
  int ik = (k < subj) ? k : k+1;
  const float* l = logits + ((size_t)(k*2048 + r))*3;
  float l0 = l[0], l1 = l[1], l2 = l[2];
  float mx = fmaxf(l0, fmaxf(l1, l2));
  float lse = mx + __logf(__expf(l0-mx) + __expf(l1-mx) + __expf(l2-mx));
  const float* yr = y + ((size_t)(ik*1024 + r))*3;
  float tl = (yr[0] > 0.5f) ? l0 : ((yr[1] > 0.5f) ? l1 : l2);
  float tot = blockSum256(lse - tl);
  if (threadIdx.x == 0) atomicAdd(clsacc, tot);
}

// ---------------- K6: pred (argmax of mean softmax over k) ----------------
__global__ __launch_bounds__(256) void k_pred(const float* __restrict__ logits,
    const float* __restrict__ y, const int* __restrict__ subj_p, float* __restrict__ predacc)
{
  int j = blockIdx.x*256 + threadIdx.x;   // 0..1023
  int subj = *subj_p;
  float p0 = 0.f, p1 = 0.f, p2 = 0.f;
  for (int k = 0; k < 14; k++) {
    const float* l = logits + ((size_t)(k*2048 + 1024 + j))*3;
    float l0 = l[0], l1 = l[1], l2 = l[2];
    float mx = fmaxf(l0, fmaxf(l1, l2));
    float e0 = __expf(l0-mx), e1 = __expf(l1-mx), e2 = __expf(l2-mx);
    float inv = 1.f/(e0+e1+e2);
    p0 += e0*inv; p1 += e1*inv; p2 += e2*inv;
  }
  int pa = 0; float pm = p0;
  if (p1 > pm) { pa = 1; pm = p1; }
  if (p2 > pm) { pa = 2; }
  const float* yt = y + ((size_t)(subj*1024 + j))*3;
  int ya = 0; float ym = yt[0];
  if (yt[1] > ym) { ya = 1; ym = yt[1]; }
  if (yt[2] > ym) { ya = 2; }
  float tot = blockSum256((pa == ya) ? 1.f : 0.f);
  if (threadIdx.x == 0) atomicAdd(predacc, tot);
}

// ---------------- K7: finalize ----------------
__global__ void k_fin(const float* __restrict__ acc, float* __restrict__ out)
{
  if (threadIdx.x == 0 && blockIdx.x == 0) {
    float s = 0.f;
    for (int k = 0; k < 14; k++) s += acc[k];
    out[0] = 0.1f * s / (14.f * 1024.f * 1024.f);
    out[1] = 0.4f * acc[14] * (2.f / (14.f*13.f)) / (1024.f*512.f);
    out[2] = acc[15] / (14.f*1024.f);
    out[3] = acc[16];
    out[4] = 1024.f;
  }
}

// ---------------- launch ----------------
extern "C" void kernel_launch(void* const* d_in, const int* in_sizes, int n_in,
                              void* d_out, int out_size, void* d_ws, size_t ws_size,
                              hipStream_t stream)
{
  (void)in_sizes; (void)n_in; (void)out_size; (void)ws_size;
  const float* x     = (const float*)d_in[0];
  const float* y     = (const float*)d_in[1];
  const float* W_add = (const float*)d_in[3];
  const float* b_add = (const float*)d_in[4];
  const float* W_cls = (const float*)d_in[5];
  const float* b_cls = (const float*)d_in[6];
  const int*   subj  = (const int*)d_in[7];

  char* ws = (char*)d_ws;
  size_t o = 0;
  auto take = [&](size_t b) { char* p = ws + o; o += (b + 255) & ~(size_t)255; return p; };
  unsigned short* X16 = (unsigned short*)take((size_t)15*1024*2048*2);   // 63 MB
  unsigned short* W16 = (unsigned short*)take((size_t)15*512*2048*2);    // 31.5 MB
  unsigned short* T16 = (unsigned short*)take((size_t)14*2048*512*2);    // 29.4 MB
  float* SQ   = (float*)take((size_t)14*2048*4);
  float* RMAX = (float*)take((size_t)14*2048*4);
  float* RINV = (float*)take((size_t)14*2048*4);
  float* SCOL = (float*)take((size_t)14*512*4);
  float* C2   = (float*)take(512);
  float* LOG  = (float*)take((size_t)14*2048*3*4);
  float* ACC  = (float*)take(256);   // [0..13] mmd_k, [14] disc, [15] cls, [16] pred

  hipMemsetAsync(SCOL, 0, 14*512*4, stream);
  hipMemsetAsync(ACC, 0, 256, stream);

  k_convert<<<2048, 256, 0, stream>>>(x, W_add, (uint2*)X16, (uint2*)W16);
  k_gemm1 <<<14*64, 256, 0, stream>>>(X16, W16, b_add, subj, T16);
  k_rowred<<<14*2048/4, 256, 0, stream>>>(T16, SQ, RMAX, RINV);
  k_colsum<<<14*16, 256, 0, stream>>>(T16, SCOL);
  k_bw    <<<14, 256, 0, stream>>>(SQ, SCOL, C2);
  k_mmd   <<<14*136, 256, 0, stream>>>(T16, SQ, C2, ACC);
  k_disc  <<<2048, 256, 0, stream>>>(T16, RMAX, RINV, ACC + 14);
  k_logits<<<14*2048/4, 256, 0, stream>>>(T16, W_cls, b_cls, LOG);
  k_cls   <<<56, 256, 0, stream>>>(LOG, y, subj, ACC + 15);
  k_pred  <<<4, 256, 0, stream>>>(LOG, y, subj, ACC + 16);
  k_fin   <<<1, 64, 0, stream>>>(ACC, (float*)d_out);
}